// Round 2
// baseline (1017.975 us; speedup 1.0000x reference)
//
#include <hip/hip_runtime.h>
#include <cstdint>

// Problem constants (B=4, C=512, H=W=256, DS=8)
#define B_    4
#define C_    512
#define H_    256
#define W_    256
#define HP_   32
#define WP_   32
#define N_    1024        // HP*WP
#define KD_   64          // C/8
#define MR_   640         // 64 (q) + 64 (k) + 512 (v)

using bf16x8 = __attribute__((ext_vector_type(8))) short;   // 8 bf16 in 4 VGPRs
using f32x4  = __attribute__((ext_vector_type(4))) float;

__device__ __forceinline__ ushort f2bf(float f) {
    union { float f; uint32_t u; } v; v.f = f;
    uint32_t r = v.u + 0x7FFF + ((v.u >> 16) & 1);          // RNE
    return (ushort)(r >> 16);
}

// ---------------------------------------------------------------------------
// Concat Wq/Wk/Wv -> Wcat [640 x 512] bf16, bq/bk/bv -> bcat [640] f32
// ---------------------------------------------------------------------------
__global__ __launch_bounds__(256) void concat_kernel(
    const float* __restrict__ Wq, const float* __restrict__ bq,
    const float* __restrict__ Wk, const float* __restrict__ bk,
    const float* __restrict__ Wv, const float* __restrict__ bv,
    ushort* __restrict__ Wcat, float* __restrict__ bcat)
{
    int tid = blockIdx.x * 256 + threadIdx.x;               // 0 .. 640*512-1
    float w;
    if (tid < 64 * C_)            w = Wq[tid];
    else if (tid < 128 * C_)      w = Wk[tid - 64 * C_];
    else                          w = Wv[tid - 128 * C_];
    Wcat[tid] = f2bf(w);
    if (tid < MR_)
        bcat[tid] = (tid < 64) ? bq[tid] : (tid < 128) ? bk[tid - 64] : bv[tid - 128];
}

// ---------------------------------------------------------------------------
// 8x8 average pool: x [B,C,256,256] -> xf f32 [B*C, 1024]   (n = ph*32+pw)
// ---------------------------------------------------------------------------
__global__ __launch_bounds__(256) void pool_kernel(
    const float* __restrict__ x, float* __restrict__ xf)
{
    int idx = blockIdx.x * 256 + threadIdx.x;
    int pw  = idx & 31;
    int ph  = (idx >> 5) & 31;
    int bc  = idx >> 10;
    const float* src = x + ((size_t)bc * H_ + ph * 8) * W_ + pw * 8;
    float s = 0.f;
#pragma unroll
    for (int r = 0; r < 8; ++r) {
        float4 a = *(const float4*)(src + (size_t)r * W_);
        float4 b = *(const float4*)(src + (size_t)r * W_ + 4);
        s += (a.x + a.y + a.z + a.w) + (b.x + b.y + b.z + b.w);
    }
    xf[(size_t)bc * N_ + ph * WP_ + pw] = s * (1.f / 64.f);
}

// ---------------------------------------------------------------------------
// Transpose+convert: xf f32 [b*512+c][1024] -> xfT bf16 [b][n][c]  (32x32 tiles)
// ---------------------------------------------------------------------------
__global__ __launch_bounds__(256) void txf_kernel(
    const float* __restrict__ xf, ushort* __restrict__ xfT)
{
    __shared__ float tile[32][33];
    const int b = blockIdx.z, c0 = blockIdx.y * 32, n0 = blockIdx.x * 32;
    const int t = threadIdx.x;
    const float* src = xf + (size_t)(b * C_ + c0) * N_ + n0;
    {
        int i = t >> 3, j = (t & 7) << 2;
        float4 v = *(const float4*)(src + (size_t)i * N_ + j);
        tile[i][j] = v.x; tile[i][j + 1] = v.y; tile[i][j + 2] = v.z; tile[i][j + 3] = v.w;
    }
    __syncthreads();
    {
        int jj = t >> 3, ii = (t & 7) << 2;
        ushort4 o;
        o.x = f2bf(tile[ii][jj]);     o.y = f2bf(tile[ii + 1][jj]);
        o.z = f2bf(tile[ii + 2][jj]); o.w = f2bf(tile[ii + 3][jj]);
        *(ushort4*)(xfT + (size_t)(b * N_ + n0 + jj) * C_ + c0 + ii) = o;
    }
}

// ---------------------------------------------------------------------------
// Transpose q/k rows of Y: Y bf16 [b][640][1024] rows 0..127 -> qkT [b][n][128]
// ---------------------------------------------------------------------------
__global__ __launch_bounds__(256) void tqk_kernel(
    const ushort* __restrict__ Y, ushort* __restrict__ qkT)
{
    __shared__ ushort tile[32][36];
    const int b = blockIdx.z, j0 = blockIdx.y * 32, n0 = blockIdx.x * 32;
    const int t = threadIdx.x;
    const ushort* src = Y + ((size_t)b * MR_ + j0) * N_ + n0;
    {
        int i = t >> 3, j = (t & 7) << 2;
        ushort4 v = *(const ushort4*)(src + (size_t)i * N_ + j);
        tile[i][j] = v.x; tile[i][j + 1] = v.y; tile[i][j + 2] = v.z; tile[i][j + 3] = v.w;
    }
    __syncthreads();
    {
        int nn = t >> 3, jj = (t & 7) << 2;
        ushort4 o;
        o.x = tile[jj][nn];     o.y = tile[jj + 1][nn];
        o.z = tile[jj + 2][nn]; o.w = tile[jj + 3][nn];
        *(ushort4*)(qkT + ((size_t)b * N_ + n0 + nn) * 128 + j0 + jj) = o;
    }
}

// ---------------------------------------------------------------------------
// bf16 MFMA GEMM:  C[m,n] = alpha * sum_k A[m][k]*B[n][k] + bias[m]
// A: [M][K] k-fast (lda), B: [N][K] k-fast (ldb).  Both bf16, fp32 accum.
// Tile 128x128, BK=32, 4 waves (2x2), 64x64 per wave via 4x4 16x16x32 MFMA.
// All dims divide tiles exactly. OUT_BF16 selects bf16 vs f32 output.
// C/D fragment mapping (m89-verified): col = lane&15, row = (lane>>4)*4 + reg.
// Staging: 2 threads/row, each loads 16 bf16 (two bf16x8 = 32 bytes) so the
// full 128x32 tile is covered (bug in prior round: only half the K staged).
// ---------------------------------------------------------------------------
template <bool OUT_BF16>
__global__ __launch_bounds__(256) void mfma_gemm(
    const ushort* __restrict__ A, long lda, long sAb,
    const ushort* __restrict__ B, long ldb, long sBb,
    void* __restrict__ Cv, long ldc, long sCb,
    int Kdim, const float* __restrict__ bias, float alpha)
{
    constexpr int BM = 128, BN = 128, BK = 32, LDP = 40;  // LDP: +8 bf16 pad (80B rows)
    __shared__ ushort As[BM * LDP];
    __shared__ ushort Bs[BN * LDP];
    const int t  = threadIdx.x;
    const int l  = t & 63;
    const int w  = t >> 6;
    const int wr = w >> 1, wc = w & 1;                    // 2x2 wave grid
    const int m0 = blockIdx.y * BM, n0 = blockIdx.x * BN;
    A += (size_t)blockIdx.z * sAb;
    B += (size_t)blockIdx.z * sBb;

    f32x4 acc[4][4] = {};

    const int srow = t >> 1, sk = (t & 1) << 4;           // staging: 128 rows, 16 k each
    const int lrow = l & 15, kg = (l >> 4) << 3;          // fragment row / k-group

    for (int kt = 0; kt < Kdim; kt += BK) {
        const ushort* pA = A + (size_t)(m0 + srow) * lda + kt + sk;
        const ushort* pB = B + (size_t)(n0 + srow) * ldb + kt + sk;
        bf16x8 av0 = *(const bf16x8*)(pA);
        bf16x8 av1 = *(const bf16x8*)(pA + 8);
        bf16x8 bv0 = *(const bf16x8*)(pB);
        bf16x8 bv1 = *(const bf16x8*)(pB + 8);
        *(bf16x8*)&As[srow * LDP + sk]     = av0;
        *(bf16x8*)&As[srow * LDP + sk + 8] = av1;
        *(bf16x8*)&Bs[srow * LDP + sk]     = bv0;
        *(bf16x8*)&Bs[srow * LDP + sk + 8] = bv1;
        __syncthreads();

        bf16x8 af[4], bfr[4];
#pragma unroll
        for (int f = 0; f < 4; ++f) {
            af[f]  = *(const bf16x8*)&As[(wr * 64 + f * 16 + lrow) * LDP + kg];
            bfr[f] = *(const bf16x8*)&Bs[(wc * 64 + f * 16 + lrow) * LDP + kg];
        }
#pragma unroll
        for (int i = 0; i < 4; ++i)
#pragma unroll
            for (int j = 0; j < 4; ++j)
                acc[i][j] = __builtin_amdgcn_mfma_f32_16x16x32_bf16(
                    af[i], bfr[j], acc[i][j], 0, 0, 0);
        __syncthreads();
    }

    const int col = l & 15, rowg = (l >> 4) << 2;
#pragma unroll
    for (int i = 0; i < 4; ++i) {
        const int gmb = m0 + wr * 64 + i * 16 + rowg;
#pragma unroll
        for (int j = 0; j < 4; ++j) {
            const int gn = n0 + wc * 64 + j * 16 + col;
#pragma unroll
            for (int r = 0; r < 4; ++r) {
                const int gm = gmb + r;
                float vv = alpha * acc[i][j][r] + (bias ? bias[gm] : 0.f);
                if constexpr (OUT_BF16)
                    ((ushort*)Cv)[(size_t)blockIdx.z * sCb + (size_t)gm * ldc + gn] = f2bf(vv);
                else
                    ((float*)Cv)[(size_t)blockIdx.z * sCb + (size_t)gm * ldc + gn] = vv;
            }
        }
    }
}

// ---------------------------------------------------------------------------
// Row softmax: attn f32 [rows,1024] -> attnb bf16 [rows,1024]. 1 block/row.
// ---------------------------------------------------------------------------
__global__ __launch_bounds__(256) void softmax_kernel(
    const float* __restrict__ attn, ushort* __restrict__ attnb)
{
    __shared__ float sm[4], ss[4];
    const float* p = attn + (size_t)blockIdx.x * N_;
    const int t = threadIdx.x;
    float4 v = *(const float4*)&p[t * 4];

    float m = fmaxf(fmaxf(v.x, v.y), fmaxf(v.z, v.w));
#pragma unroll
    for (int off = 32; off > 0; off >>= 1) m = fmaxf(m, __shfl_down(m, off));
    const int wid = t >> 6, lane = t & 63;
    if (lane == 0) sm[wid] = m;
    __syncthreads();
    m = fmaxf(fmaxf(sm[0], sm[1]), fmaxf(sm[2], sm[3]));

    v.x = __expf(v.x - m); v.y = __expf(v.y - m);
    v.z = __expf(v.z - m); v.w = __expf(v.w - m);
    float s = v.x + v.y + v.z + v.w;
#pragma unroll
    for (int off = 32; off > 0; off >>= 1) s += __shfl_down(s, off);
    if (lane == 0) ss[wid] = s;
    __syncthreads();
    s = ss[0] + ss[1] + ss[2] + ss[3];

    const float inv = 1.f / s;
    ushort4 o;
    o.x = f2bf(v.x * inv); o.y = f2bf(v.y * inv);
    o.z = f2bf(v.z * inv); o.w = f2bf(v.w * inv);
    *(ushort4*)(attnb + (size_t)blockIdx.x * N_ + t * 4) = o;
}

// ---------------------------------------------------------------------------
// out[bc,y,x] = osm[bc, (y/8)*32 + x/8] + x[bc,y,x]
// ---------------------------------------------------------------------------
__global__ __launch_bounds__(256) void final_kernel(
    const float* __restrict__ x, const float* __restrict__ osm,
    float* __restrict__ out)
{
    size_t f   = (size_t)blockIdx.x * 256 + threadIdx.x;
    int    x4  = (int)(f & 63);
    int    y   = (int)((f >> 6) & 255);
    size_t bc  = f >> 14;
    int    n   = ((y >> 3) << 5) + (x4 >> 1);
    float  s   = osm[(bc << 10) + n];
    float4 xv  = ((const float4*)x)[f];
    ((float4*)out)[f] = make_float4(xv.x + s, xv.y + s, xv.z + s, xv.w + s);
}

// ---------------------------------------------------------------------------
extern "C" void kernel_launch(void* const* d_in, const int* in_sizes, int n_in,
                              void* d_out, int out_size, void* d_ws, size_t ws_size,
                              hipStream_t stream)
{
    const float* x  = (const float*)d_in[0];
    const float* Wq = (const float*)d_in[1];
    const float* bq = (const float*)d_in[2];
    const float* Wk = (const float*)d_in[3];
    const float* bk = (const float*)d_in[4];
    const float* Wv = (const float*)d_in[5];
    const float* bv = (const float*)d_in[6];
    float* out = (float*)d_out;

    // ---- scratch in d_out's batch-3 quarter (dead until final writes) ----
    float*  scratch = out + (size_t)3 * C_ * H_ * W_;     // 33,554,432 floats
    float*  xf    = scratch;                              // 2,097,152 f
    ushort* xfT   = (ushort*)(xf + 2097152);              // 2,097,152 bf16
    ushort* Y     = xfT + 2097152;                        // 2,621,440 bf16  [b][640][1024]
    ushort* qkT   = Y + 2621440;                          //   524,288 bf16  [b][1024][128]
    float*  attn  = (float*)(qkT + 524288);               // 4,194,304 f     [b][1024][1024]
    ushort* attnb = (ushort*)(attn + 4194304);            // 4,194,304 bf16
    ushort* Wcat  = attnb + 4194304;                      //   327,680 bf16
    float*  bcat  = (float*)(Wcat + 327680);              //       640 f   (total ~11.2M f)

    const bool full_osm = ws_size >= (size_t)B_ * C_ * N_ * sizeof(float);  // 8 MB
    float* osm = (float*)d_ws;

    // 1) concat weights -> bf16
    concat_kernel<<<dim3(1280), dim3(256), 0, stream>>>(Wq, bq, Wk, bk, Wv, bv, Wcat, bcat);

    // 2) avg-pool 8x8 (fp32)
    pool_kernel<<<dim3((B_ * C_ * N_) / 256), dim3(256), 0, stream>>>(x, xf);

    // 3) transpose+convert pooled features: xfT[b][n][c] bf16
    txf_kernel<<<dim3(32, 16, 4), dim3(256), 0, stream>>>(xf, xfT);

    // 4) fused QKV (bf16 MFMA): Y[b][j][n] = Wcat[j,:]·xfT[b][n,:] + bcat[j]
    mfma_gemm<true><<<dim3(8, 5, 4), dim3(256), 0, stream>>>(
        Wcat, 512, 0,
        xfT, 512, (long)N_ * C_,
        Y, 1024, (long)MR_ * N_,
        C_, bcat, 1.f);

    // 5) transpose q/k rows: qkT[b][n][j], j in [0,128)
    tqk_kernel<<<dim3(32, 4, 4), dim3(256), 0, stream>>>(Y, qkT);

    // 6) energy (bf16 MFMA): attn[b][n][m] = 0.125 * qkT[n][0:64]·qkT[m][64:128]
    mfma_gemm<false><<<dim3(8, 8, 4), dim3(256), 0, stream>>>(
        qkT, 128, (long)N_ * 128,
        qkT + 64, 128, (long)N_ * 128,
        attn, 1024, (long)N_ * N_,
        KD_, nullptr, 0.125f);

    // 7) softmax -> bf16
    softmax_kernel<<<dim3(B_ * N_), dim3(256), 0, stream>>>(attn, attnb);

    if (full_osm) {
        // 8) PV (bf16 MFMA): osm[b][d][m] = v[d,:]·attnb[m,:]
        mfma_gemm<false><<<dim3(8, 4, 4), dim3(256), 0, stream>>>(
            Y + 128 * 1024, 1024, (long)MR_ * N_,
            attnb, 1024, (long)N_ * N_,
            osm, 1024, (long)C_ * N_,
            N_, nullptr, 1.f);
        // 9) upsample + residual (clobbers scratch; osm lives in ws)
        final_kernel<<<dim3((B_ * C_ * H_ * W_ / 4) / 256), dim3(256), 0, stream>>>(
            x, osm, out);
    } else {
        for (int b = 0; b < B_; ++b) {
            mfma_gemm<false><<<dim3(8, 4, 1), dim3(256), 0, stream>>>(
                Y + 128 * 1024 + (size_t)b * MR_ * N_, 1024, 0,
                attnb + (size_t)b * N_ * N_, 1024, 0,
                osm, 1024, 0,
                N_, nullptr, 1.f);
            final_kernel<<<dim3((C_ * H_ * W_ / 4) / 256), dim3(256), 0, stream>>>(
                x + (size_t)b * C_ * H_ * W_, osm, out + (size_t)b * C_ * H_ * W_);
        }
    }
}